// Round 14
// baseline (155.177 us; speedup 1.0000x reference)
//
#include <hip/hip_runtime.h>
#include <hip/hip_bf16.h>
#include <stdint.h>

// FlatCritic: B=128, L=512, D_DESC=768, D_STD=128, D_ACT=128, D_CTX=1152, H=512
// out = [q (B*L f32), emb (B*L*128 f32)]
//
// v14 = v12's fused_main (verbatim, known-good ~110us) + ONE fused prologue
// kernel: blocks 0..127 compute cc[b] (fp32 exact) then qinv[b] in-block;
// blocks 128..255 pack weight fragments concurrently. 4 launches -> 2.
// (v13 lesson: hipLaunchCooperativeKernel does not survive graph capture.)

typedef __attribute__((ext_vector_type(8))) short short8_t;
typedef __attribute__((ext_vector_type(4))) short short4_t;
typedef __attribute__((ext_vector_type(4))) float f32x4;

__device__ inline unsigned short f2bf(float f) {
  union { float f; unsigned u; } v; v.f = f;
  unsigned r = v.u + 0x7FFFu + ((v.u >> 16) & 1u);
  return (unsigned short)(r >> 16);
}

// A-frag pack (mb-major): dst[((mb*NKS+ks)*64+l)*8+j] = bf16(src[(k0+ks*32+(l>>4)*8+j)*ldc + mb*16+(l&15)])
__device__ inline void pack_frags(const float* __restrict__ src, int ldc, int k0, int NKS,
                                  unsigned short* __restrict__ dst, int total, int tid, int n) {
  for (int fi = tid; fi < total; fi += n) {
    int j = fi & 7, lane = (fi >> 3) & 63, rest = fi >> 9;
    int ks = rest % NKS, mb = rest / NKS;
    int c = mb * 16 + (lane & 15);
    int k = k0 + ks * 32 + ((lane >> 4) << 3) + j;
    dst[fi] = f2bf(src[(size_t)k * ldc + c]);
  }
}

// ---------------- prologue: cc + qinv (blocks 0..127) | pack (blocks 128..255) ----------------
__global__ __launch_bounds__(512) void prologue_fused(
    const float* __restrict__ instr, const float* __restrict__ state,
    const float* __restrict__ hidden,
    const float* __restrict__ Wd, const float* __restrict__ Ws,
    const float* __restrict__ W1, const float* __restrict__ W2,
    const float* __restrict__ b1, const float* __restrict__ b2,
    const float* __restrict__ W3, const float* __restrict__ b3,
    unsigned short* __restrict__ wdf, unsigned short* __restrict__ wsf,
    unsigned short* __restrict__ w1f, unsigned short* __restrict__ w2f,
    float* __restrict__ cc, float* __restrict__ qinv) {
  __shared__ float ctx[1152];
  __shared__ float h1s[512];
  __shared__ float red[512];
  int bid = blockIdx.x, t = threadIdx.x;

  if (bid < 128) {
    int b = bid;
    ctx[t] = instr[b * 512 + t];
    ctx[512 + t] = state[b * 512 + t];
    if (t < 128) ctx[1024 + t] = hidden[b * 128 + t];
    __syncthreads();

    // cc[b][t] = b1[t] + sum_d ctx[d] * W1[d][t]  (fp32 exact, coalesced)
    float a = 0.f;
    const float* wp = W1 + t;
    #pragma unroll 8
    for (int d = 0; d < 1152; ++d) a = fmaf(ctx[d], wp[(size_t)d * 512], a);
    a += b1[t];
    cc[b * 512 + t] = a;
    h1s[t] = fmaxf(a, 0.f);
    __syncthreads();

    // qinv[b] = relu(b3 + sum_t relu(b2[t] + sum_c h1s[c]*W2[c][t]) * W3[t])
    float q = b2[t];
    const float* w2p = W2 + t;
    #pragma unroll 8
    for (int c = 0; c < 512; ++c) q = fmaf(h1s[c], w2p[(size_t)c * 512], q);
    red[t] = fmaxf(q, 0.f) * W3[t];
    __syncthreads();
    for (int s = 256; s > 0; s >>= 1) { if (t < s) red[t] += red[t + s]; __syncthreads(); }
    if (t == 0) qinv[b] = fmaxf(red[0] + b3[0], 0.f);
  } else {
    int tid = (bid - 128) * 512 + t, n = 128 * 512;
    pack_frags(Wd, 128, 0,    24, wdf,  98304,  tid, n);   // desc proj  [8mb][24ks]
    pack_frags(Ws, 128, 0,    4,  wsf,  16384,  tid, n);   // std proj   [8mb][4ks]
    pack_frags(W1, 512, 1152, 4,  w1f,  65536,  tid, n);   // W1[1152:]  [32mb][4ks]
    pack_frags(W2, 512, 0,    16, w2f,  262144, tid, n);   // W2         [32mb][16ks]
  }
}

// ---------------- FUSED main: 64-row tiles, 512 threads, grid (8,128) (= v12) ----------------
__global__ __launch_bounds__(512, 4) void fused_main(
    const float* __restrict__ adesc, const float* __restrict__ astd,
    const int* __restrict__ type_ids, const int* __restrict__ lengths,
    const float* __restrict__ bdesc, const float* __restrict__ bstd,
    const float* __restrict__ b2, const float* __restrict__ W3, const float* __restrict__ b3,
    const unsigned short* __restrict__ wdf, const unsigned short* __restrict__ wsf,
    const unsigned short* __restrict__ w1f, const unsigned short* __restrict__ w2f,
    const float* __restrict__ cc, const float* __restrict__ qinv,
    float* __restrict__ embout, float* __restrict__ qout) {
  int b = blockIdx.y, lt = blockIdx.x;
  int l0 = lt * 64;
  int t = threadIdx.x;
  int len = lengths[b];
  int nv = len - l0; nv = nv < 0 ? 0 : (nv > 64 ? 64 : nv);
  f32x4 zero4 = {0.f, 0.f, 0.f, 0.f};

  if (nv == 0) {  // fully-invalid tile: emb = 0, q = q_inv
    float qv = qinv[b];
    if (t < 64) qout[(size_t)b * 512 + l0 + t] = qv;
    f32x4* ep = (f32x4*)(embout + (size_t)(b * 512 + l0) * 128);
    #pragma unroll
    for (int i = 0; i < 4; ++i) ep[t + i * 512] = zero4;
    return;
  }

  // Union arena: [0..17408) act0 / E, [17408..34816) act1  (proj+S1 phases)
  //              whole [0..32768) shorts = h1[64][512] swizzled (S2 phase)
  __shared__ __align__(16) unsigned short arena[64 * 512];
  __shared__ float qpart[8][64];
  __shared__ int typeL[64];
  int w = t >> 6, l = t & 63, g = l >> 4, ln = l & 15;

  if (t < 64) typeL[t] = type_ids[b * 512 + l0 + t];

  const float* descB = adesc + (size_t)(b * 512 + l0) * 768;
  const float* stdB  = astd  + (size_t)(b * 512 + l0) * 128;

  __syncthreads();  // typeL ready

  f32x4 acc[4][4];            // unified accumulator: proj uses acc[0][*]
  f32x4 (&acc_e)[4] = acc[0];

  // ===== Phase E: embT[k=0..127][r=0..63]; wave w owns mb=w (k = w*16..w*16+15)
  {
    f32x4 stg[4];
    int r0 = t >> 5, c4 = t & 31;  // rows r0+16i, col quad c4

    auto issue = [&](int kc) {
      bool isStd = (kc == 6);
      #pragma unroll
      for (int i = 0; i < 4; ++i) {
        int r = r0 + i * 16;
        bool ok = (r < nv) && ((typeL[r] == 0) != isStd);
        f32x4 v = zero4;
        if (ok) v = isStd ? *(const f32x4*)(stdB + (size_t)r * 128 + c4 * 4)
                          : *(const f32x4*)(descB + (size_t)r * 768 + kc * 128 + c4 * 4);
        stg[i] = v;
      }
    };
    auto writebuf = [&](int kc) {
      unsigned short* buf = arena + (kc & 1) * 8704;
      #pragma unroll
      for (int i = 0; i < 4; ++i) {
        short4_t p;
        p[0] = (short)f2bf(stg[i][0]); p[1] = (short)f2bf(stg[i][1]);
        p[2] = (short)f2bf(stg[i][2]); p[3] = (short)f2bf(stg[i][3]);
        *(short4_t*)&buf[(r0 + i * 16) * 136 + c4 * 4] = p;
      }
    };

    issue(0); writebuf(0);

    #pragma unroll
    for (int nb = 0; nb < 4; ++nb) acc_e[nb] = zero4;

    for (int kc = 0; kc < 7; ++kc) {
      __syncthreads();
      if (kc < 6) issue(kc + 1);
      const unsigned short* buf = arena + (kc & 1) * 8704;
      bool isStd = (kc == 6);
      #pragma unroll
      for (int ks = 0; ks < 4; ++ks) {
        const unsigned short* ap = isStd ? (wsf + (((w * 4 + ks) * 64 + l) << 3))
                                         : (wdf + (((w * 24 + kc * 4 + ks) * 64 + l) << 3));
        short8_t a = *(const short8_t*)ap;
        #pragma unroll
        for (int nb = 0; nb < 4; ++nb) {
          short8_t bb = *(const short8_t*)&buf[(nb * 16 + ln) * 136 + ks * 32 + g * 8];
          acc_e[nb] = __builtin_amdgcn_mfma_f32_16x16x32_bf16(a, bb, acc_e[nb], 0, 0, 0);
        }
      }
      if (kc < 6) writebuf(kc + 1);
    }
  }
  __syncthreads();  // last proj MFMAs (read act0) done -> reuse act0 as E

  // epilogue E: masked bias + embout f32 store + bf16 -> E (arena[0..17408))
  {
    unsigned short* E = arena;
    int k0 = w * 16 + g * 4;
    f32x4 bd4 = *(const f32x4*)(bdesc + k0);
    f32x4 bs4 = *(const f32x4*)(bstd + k0);
    #pragma unroll
    for (int nb = 0; nb < 4; ++nb) {
      int r = nb * 16 + ln;
      f32x4 e = acc_e[nb];
      if (r < nv) { f32x4 bias = (typeL[r] == 0) ? bd4 : bs4; e = e + bias; }
      else e = zero4;
      *(f32x4*)(embout + (size_t)(b * 512 + l0 + r) * 128 + k0) = e;
      short4_t p; p[0] = (short)f2bf(e[0]); p[1] = (short)f2bf(e[1]);
      p[2] = (short)f2bf(e[2]); p[3] = (short)f2bf(e[3]);
      *(short4_t*)&E[r * 136 + k0] = p;
    }
  }
  __syncthreads();  // E complete

  // ===== S1: H1T[c1][r] = cc[b][c1] + sum_k W1e[k][c1]*E[r][k]  (B from LDS E)
  #pragma unroll
  for (int mbi = 0; mbi < 4; ++mbi) {
    f32x4 ccv = *(const f32x4*)(cc + (size_t)b * 512 + (w * 4 + mbi) * 16 + g * 4);
    #pragma unroll
    for (int nb = 0; nb < 4; ++nb) acc[mbi][nb] = ccv;
  }
  {
    const unsigned short* E = arena;
    #pragma unroll
    for (int kk = 0; kk < 4; ++kk) {
      int ks = (kk + w) & 3;  // wave-staggered K order
      short8_t bfr[4];
      #pragma unroll
      for (int nb = 0; nb < 4; ++nb)
        bfr[nb] = *(const short8_t*)&E[(nb * 16 + ln) * 136 + ks * 32 + g * 8];
      #pragma unroll
      for (int mbi = 0; mbi < 4; ++mbi) {
        short8_t a = *(const short8_t*)(w1f + ((((w * 4 + mbi) * 4 + ks) * 64 + l) << 3));
        #pragma unroll
        for (int nb = 0; nb < 4; ++nb)
          acc[mbi][nb] = __builtin_amdgcn_mfma_f32_16x16x32_bf16(a, bfr[nb], acc[mbi][nb], 0, 0, 0);
      }
    }
  }
  __syncthreads();  // all E reads done -> arena free for h1

  // relu + pack H1 bf16 -> arena as swizzled [64][512]
  #pragma unroll
  for (int mbi = 0; mbi < 4; ++mbi) {
    int c0 = (w * 4 + mbi) * 16 + g * 4;
    #pragma unroll
    for (int nb = 0; nb < 4; ++nb) {
      int r = nb * 16 + ln;
      f32x4 v = acc[mbi][nb];
      short4_t p;
      p[0] = (short)f2bf(fmaxf(v[0], 0.f)); p[1] = (short)f2bf(fmaxf(v[1], 0.f));
      p[2] = (short)f2bf(fmaxf(v[2], 0.f)); p[3] = (short)f2bf(fmaxf(v[3], 0.f));
      *(short4_t*)&arena[r * 512 + (c0 ^ ((r & 7) << 3))] = p;
    }
  }
  __syncthreads();

  // ===== S2: H2T[c2][r] = b2[c2] + sum_c1 W2[c1][c2]*H1[r][c1]  (acc reused)
  #pragma unroll
  for (int mbi = 0; mbi < 4; ++mbi) {
    f32x4 b2v = *(const f32x4*)(b2 + (w * 4 + mbi) * 16 + g * 4);
    #pragma unroll
    for (int nb = 0; nb < 4; ++nb) acc[mbi][nb] = b2v;
  }
  #pragma unroll
  for (int kk = 0; kk < 16; ++kk) {
    int ks = (kk + 2 * w) & 15;  // wave-staggered K order
    short8_t bfr[4];
    #pragma unroll
    for (int nb = 0; nb < 4; ++nb) {
      int row = nb * 16 + ln;
      bfr[nb] = *(const short8_t*)&arena[row * 512 + ((ks * 32 + g * 8) ^ ((row & 7) << 3))];
    }
    #pragma unroll
    for (int mbi = 0; mbi < 4; ++mbi) {
      short8_t a = *(const short8_t*)(w2f + ((((w * 4 + mbi) * 16 + ks) * 64 + l) << 3));
      #pragma unroll
      for (int nb = 0; nb < 4; ++nb)
        acc[mbi][nb] = __builtin_amdgcn_mfma_f32_16x16x32_bf16(a, bfr[nb], acc[mbi][nb], 0, 0, 0);
    }
  }

  // ===== S3: q[r] = relu(b3 + sum_c2 relu(H2)*W3)
  float part[4] = {0.f, 0.f, 0.f, 0.f};
  #pragma unroll
  for (int mbi = 0; mbi < 4; ++mbi) {
    int c0 = (w * 4 + mbi) * 16 + g * 4;
    f32x4 w3v = *(const f32x4*)(W3 + c0);
    #pragma unroll
    for (int nb = 0; nb < 4; ++nb) {
      f32x4 v = acc[mbi][nb];
      part[nb] += fmaxf(v[0], 0.f) * w3v[0] + fmaxf(v[1], 0.f) * w3v[1]
                + fmaxf(v[2], 0.f) * w3v[2] + fmaxf(v[3], 0.f) * w3v[3];
    }
  }
  #pragma unroll
  for (int nb = 0; nb < 4; ++nb) {
    float p = part[nb];
    p += __shfl_xor(p, 16, 64);
    p += __shfl_xor(p, 32, 64);
    if (g == 0) qpart[w][nb * 16 + ln] = p;
  }
  __syncthreads();
  if (t < 64) {
    float q = qpart[0][t] + qpart[1][t] + qpart[2][t] + qpart[3][t]
            + qpart[4][t] + qpart[5][t] + qpart[6][t] + qpart[7][t] + b3[0];
    qout[(size_t)b * 512 + l0 + t] = fmaxf(q, 0.f);
  }
}

extern "C" void kernel_launch(void* const* d_in, const int* in_sizes, int n_in,
                              void* d_out, int out_size, void* d_ws, size_t ws_size,
                              hipStream_t stream) {
  (void)in_sizes; (void)n_in; (void)out_size; (void)ws_size;
  const float* instr  = (const float*)d_in[0];
  const float* state  = (const float*)d_in[1];
  const float* hidden = (const float*)d_in[2];
  const float* adesc  = (const float*)d_in[3];
  const float* astd   = (const float*)d_in[4];
  const int*   tids   = (const int*)d_in[5];
  const int*   lens   = (const int*)d_in[6];
  const float* Wd = (const float*)d_in[7];
  const float* bd = (const float*)d_in[8];
  const float* Ws = (const float*)d_in[9];
  const float* bs = (const float*)d_in[10];
  const float* W1 = (const float*)d_in[11];
  const float* b1 = (const float*)d_in[12];
  const float* W2 = (const float*)d_in[13];
  const float* b2 = (const float*)d_in[14];
  const float* W3 = (const float*)d_in[15];
  const float* b3 = (const float*)d_in[16];

  float* qout = (float*)d_out;
  float* embout = qout + 128 * 512;

  char* ws = (char*)d_ws;
  unsigned short* wdf  = (unsigned short*)(ws);             // 196608 B
  unsigned short* wsf  = (unsigned short*)(ws + 196608);    //  32768 B
  unsigned short* w1f  = (unsigned short*)(ws + 229376);    // 131072 B
  unsigned short* w2f  = (unsigned short*)(ws + 360448);    // 524288 B
  float* cc   = (float*)(ws + 884736);                      // 262144 B
  float* qinv = (float*)(ws + 1146880);                     // 512 B

  prologue_fused<<<256, 512, 0, stream>>>(instr, state, hidden, Wd, Ws, W1, W2,
                                          b1, b2, W3, b3, wdf, wsf, w1f, w2f,
                                          cc, qinv);
  dim3 grid(8, 128);
  fused_main<<<grid, 512, 0, stream>>>(adesc, astd, tids, lens, bd, bs, b2, W3, b3,
                                       wdf, wsf, w1f, w2f, cc, qinv, embout, qout);
}

// Round 15
// 103.902 us; speedup vs baseline: 1.4935x; 1.4935x over previous
//
#include <hip/hip_runtime.h>
#include <hip/hip_bf16.h>
#include <stdint.h>

// FlatCritic: B=128, L=512, D_DESC=768, D_STD=128, D_ACT=128, D_CTX=1152, H=512
// out = [q (B*L f32), emb (B*L*128 f32)]
//
// v15 = v12 fused_main (verbatim, <112us) + traffic-minimal prologue:
//   ctx_cc (302 MB W1 re-reads) -> cc_gemm MFMA w/ packed w1cf (~5 MB)
//   qinv   (134 MB W2 re-reads) -> qinv_gemm MFMA on w2f + atomicAdd (~2 MB)
// Ledger: round12+14 showed prologue ~37-43us warm; this cuts it to ~12.

typedef __attribute__((ext_vector_type(8))) short short8_t;
typedef __attribute__((ext_vector_type(4))) short short4_t;
typedef __attribute__((ext_vector_type(4))) float f32x4;

__device__ inline unsigned short f2bf(float f) {
  union { float f; unsigned u; } v; v.f = f;
  unsigned r = v.u + 0x7FFFu + ((v.u >> 16) & 1u);
  return (unsigned short)(r >> 16);
}

// A-frag pack (mb-major): dst[((mb*NKS+ks)*64+l)*8+j] = bf16(src[(k0+ks*32+(l>>4)*8+j)*ldc + mb*16+(l&15)])
__device__ inline void pack_frags(const float* __restrict__ src, int ldc, int k0, int NKS,
                                  unsigned short* __restrict__ dst, int total, int tid, int n) {
  for (int fi = tid; fi < total; fi += n) {
    int j = fi & 7, lane = (fi >> 3) & 63, rest = fi >> 9;
    int ks = rest % NKS, mb = rest / NKS;
    int c = mb * 16 + (lane & 15);
    int k = k0 + ks * 32 + ((lane >> 4) << 3) + j;
    dst[fi] = f2bf(src[(size_t)k * ldc + c]);
  }
}

__global__ __launch_bounds__(256) void prep_pack(
    const float* __restrict__ Wd, const float* __restrict__ Ws,
    const float* __restrict__ W1, const float* __restrict__ W2,
    unsigned short* __restrict__ wdf, unsigned short* __restrict__ wsf,
    unsigned short* __restrict__ w1f, unsigned short* __restrict__ w2f,
    unsigned short* __restrict__ w1cf) {
  int tid = blockIdx.x * 256 + threadIdx.x, n = gridDim.x * 256;
  pack_frags(Wd, 128, 0,    24, wdf,  98304,  tid, n);   // desc proj  [8mb][24ks]
  pack_frags(Ws, 128, 0,    4,  wsf,  16384,  tid, n);   // std proj   [8mb][4ks]
  pack_frags(W1, 512, 1152, 4,  w1f,  65536,  tid, n);   // W1[1152:]  [32mb][4ks]
  pack_frags(W2, 512, 0,    16, w2f,  262144, tid, n);   // W2         [32mb][16ks]
  pack_frags(W1, 512, 0,    36, w1cf, 589824, tid, n);   // W1[:1152]  [32mb][36ks]
}

// ---------------- cc_gemm: cc[b][c] = b1[c] + ctx(b).W1[:1152,c]  (bf16 MFMA) ----------------
// grid (8 jt, 4 bt), 256 thr. Block: rows bt*32..+32, cols jt*64..+64, K=1152 (9 chunks of 128).
__global__ __launch_bounds__(256, 4) void cc_gemm(
    const float* __restrict__ instr, const float* __restrict__ state,
    const float* __restrict__ hidden, const unsigned short* __restrict__ w1cf,
    const float* __restrict__ b1, float* __restrict__ cc) {
  int jt = blockIdx.x, bt = blockIdx.y;
  int t = threadIdx.x;
  int w = t >> 6, l = t & 63, g = l >> 4, ln = l & 15;
  f32x4 zero4 = {0.f, 0.f, 0.f, 0.f};

  __shared__ __align__(16) unsigned short buf[2][32 * 136];

  int r0 = t >> 5, c4 = t & 31;  // staging: rows r0+8i, col-quad c4
  int rbase = bt * 32;

  f32x4 stg[4];
  auto issue = [&](int kc) {
    #pragma unroll
    for (int i = 0; i < 4; ++i) {
      int r = rbase + r0 + i * 8;
      f32x4 v;
      if (kc < 4)      v = *(const f32x4*)(instr + (size_t)r * 512 + kc * 128 + c4 * 4);
      else if (kc < 8) v = *(const f32x4*)(state + (size_t)r * 512 + (kc - 4) * 128 + c4 * 4);
      else             v = *(const f32x4*)(hidden + (size_t)r * 128 + c4 * 4);
      stg[i] = v;
    }
  };
  auto writebuf = [&](int kc) {
    unsigned short* bp = buf[kc & 1];
    #pragma unroll
    for (int i = 0; i < 4; ++i) {
      short4_t p;
      p[0] = (short)f2bf(stg[i][0]); p[1] = (short)f2bf(stg[i][1]);
      p[2] = (short)f2bf(stg[i][2]); p[3] = (short)f2bf(stg[i][3]);
      *(short4_t*)&bp[(r0 + i * 8) * 136 + c4 * 4] = p;
    }
  };

  issue(0); writebuf(0);

  f32x4 acc[2] = {zero4, zero4};
  int mb = jt * 4 + w;

  for (int kc = 0; kc < 9; ++kc) {
    __syncthreads();
    if (kc < 8) issue(kc + 1);
    const unsigned short* bp = buf[kc & 1];
    #pragma unroll
    for (int ks = 0; ks < 4; ++ks) {
      short8_t a = *(const short8_t*)(w1cf + ((((size_t)mb * 36 + kc * 4 + ks) * 64 + l) << 3));
      #pragma unroll
      for (int nb = 0; nb < 2; ++nb) {
        short8_t bb = *(const short8_t*)&bp[(nb * 16 + ln) * 136 + ks * 32 + g * 8];
        acc[nb] = __builtin_amdgcn_mfma_f32_16x16x32_bf16(a, bb, acc[nb], 0, 0, 0);
      }
    }
    if (kc < 8) writebuf(kc + 1);
  }

  int c0 = jt * 64 + w * 16 + g * 4;
  f32x4 b1v = *(const f32x4*)(b1 + c0);
  #pragma unroll
  for (int nb = 0; nb < 2; ++nb) {
    int r = rbase + nb * 16 + ln;
    *(f32x4*)(cc + (size_t)r * 512 + c0) = acc[nb] + b1v;
  }
}

// ---------------- qinv_gemm: qinv[b] += sum_c relu(b2[c] + relu(cc[b]).W2[:,c]) * W3[c] ----------------
// grid (8 jt, 4 bt), 256 thr. K=512 (4 chunks of 128). A = w2f frags (pre-packed).
__global__ __launch_bounds__(256, 4) void qinv_gemm(
    const float* __restrict__ cc, const unsigned short* __restrict__ w2f,
    const float* __restrict__ b2, const float* __restrict__ W3,
    float* __restrict__ qinv) {
  int jt = blockIdx.x, bt = blockIdx.y;
  int t = threadIdx.x;
  int w = t >> 6, l = t & 63, g = l >> 4, ln = l & 15;
  f32x4 zero4 = {0.f, 0.f, 0.f, 0.f};

  __shared__ __align__(16) unsigned short buf[2][32 * 136];

  int r0 = t >> 5, c4 = t & 31;
  int rbase = bt * 32;

  f32x4 stg[4];
  auto issue = [&](int kc) {
    #pragma unroll
    for (int i = 0; i < 4; ++i) {
      int r = rbase + r0 + i * 8;
      f32x4 v = *(const f32x4*)(cc + (size_t)r * 512 + kc * 128 + c4 * 4);
      v[0] = fmaxf(v[0], 0.f); v[1] = fmaxf(v[1], 0.f);
      v[2] = fmaxf(v[2], 0.f); v[3] = fmaxf(v[3], 0.f);
      stg[i] = v;
    }
  };
  auto writebuf = [&](int kc) {
    unsigned short* bp = buf[kc & 1];
    #pragma unroll
    for (int i = 0; i < 4; ++i) {
      short4_t p;
      p[0] = (short)f2bf(stg[i][0]); p[1] = (short)f2bf(stg[i][1]);
      p[2] = (short)f2bf(stg[i][2]); p[3] = (short)f2bf(stg[i][3]);
      *(short4_t*)&bp[(r0 + i * 8) * 136 + c4 * 4] = p;
    }
  };

  issue(0); writebuf(0);

  f32x4 acc[2] = {zero4, zero4};
  int mb = jt * 4 + w;

  for (int kc = 0; kc < 4; ++kc) {
    __syncthreads();
    if (kc < 3) issue(kc + 1);
    const unsigned short* bp = buf[kc & 1];
    #pragma unroll
    for (int ks = 0; ks < 4; ++ks) {
      short8_t a = *(const short8_t*)(w2f + ((((size_t)mb * 16 + kc * 4 + ks) * 64 + l) << 3));
      #pragma unroll
      for (int nb = 0; nb < 2; ++nb) {
        short8_t bb = *(const short8_t*)&bp[(nb * 16 + ln) * 136 + ks * 32 + g * 8];
        acc[nb] = __builtin_amdgcn_mfma_f32_16x16x32_bf16(a, bb, acc[nb], 0, 0, 0);
      }
    }
    if (kc < 3) writebuf(kc + 1);
  }

  // H2 cols c = jt*64 + w*16 + g*4 + reg, rows b = rbase + nb*16 + ln
  int c0 = jt * 64 + w * 16 + g * 4;
  f32x4 b2v = *(const f32x4*)(b2 + c0);
  f32x4 w3v = *(const f32x4*)(W3 + c0);
  #pragma unroll
  for (int nb = 0; nb < 2; ++nb) {
    f32x4 v = acc[nb];
    float p = fmaxf(v[0] + b2v[0], 0.f) * w3v[0] + fmaxf(v[1] + b2v[1], 0.f) * w3v[1]
            + fmaxf(v[2] + b2v[2], 0.f) * w3v[2] + fmaxf(v[3] + b2v[3], 0.f) * w3v[3];
    p += __shfl_xor(p, 16, 64);
    p += __shfl_xor(p, 32, 64);
    if (g == 0) atomicAdd(&qinv[rbase + nb * 16 + ln], p);
  }
}

// ---------------- FUSED main: 64-row tiles, 512 threads, grid (8,128) (= v12) ----------------
__global__ __launch_bounds__(512, 4) void fused_main(
    const float* __restrict__ adesc, const float* __restrict__ astd,
    const int* __restrict__ type_ids, const int* __restrict__ lengths,
    const float* __restrict__ bdesc, const float* __restrict__ bstd,
    const float* __restrict__ b2, const float* __restrict__ W3, const float* __restrict__ b3,
    const unsigned short* __restrict__ wdf, const unsigned short* __restrict__ wsf,
    const unsigned short* __restrict__ w1f, const unsigned short* __restrict__ w2f,
    const float* __restrict__ cc, const float* __restrict__ qinv,
    float* __restrict__ embout, float* __restrict__ qout) {
  int b = blockIdx.y, lt = blockIdx.x;
  int l0 = lt * 64;
  int t = threadIdx.x;
  int len = lengths[b];
  int nv = len - l0; nv = nv < 0 ? 0 : (nv > 64 ? 64 : nv);
  f32x4 zero4 = {0.f, 0.f, 0.f, 0.f};

  if (nv == 0) {  // fully-invalid tile: emb = 0, q = relu(qinv_raw + b3)
    float qv = fmaxf(qinv[b] + b3[0], 0.f);
    if (t < 64) qout[(size_t)b * 512 + l0 + t] = qv;
    f32x4* ep = (f32x4*)(embout + (size_t)(b * 512 + l0) * 128);
    #pragma unroll
    for (int i = 0; i < 4; ++i) ep[t + i * 512] = zero4;
    return;
  }

  // Union arena: [0..17408) act0 / E, [17408..34816) act1  (proj+S1 phases)
  //              whole [0..32768) shorts = h1[64][512] swizzled (S2 phase)
  __shared__ __align__(16) unsigned short arena[64 * 512];
  __shared__ float qpart[8][64];
  __shared__ int typeL[64];
  int w = t >> 6, l = t & 63, g = l >> 4, ln = l & 15;

  if (t < 64) typeL[t] = type_ids[b * 512 + l0 + t];

  const float* descB = adesc + (size_t)(b * 512 + l0) * 768;
  const float* stdB  = astd  + (size_t)(b * 512 + l0) * 128;

  __syncthreads();  // typeL ready

  f32x4 acc[4][4];            // unified accumulator: proj uses acc[0][*]
  f32x4 (&acc_e)[4] = acc[0];

  // ===== Phase E: embT[k=0..127][r=0..63]; wave w owns mb=w (k = w*16..w*16+15)
  {
    f32x4 stg[4];
    int r0 = t >> 5, c4 = t & 31;  // rows r0+16i, col quad c4

    auto issue = [&](int kc) {
      bool isStd = (kc == 6);
      #pragma unroll
      for (int i = 0; i < 4; ++i) {
        int r = r0 + i * 16;
        bool ok = (r < nv) && ((typeL[r] == 0) != isStd);
        f32x4 v = zero4;
        if (ok) v = isStd ? *(const f32x4*)(stdB + (size_t)r * 128 + c4 * 4)
                          : *(const f32x4*)(descB + (size_t)r * 768 + kc * 128 + c4 * 4);
        stg[i] = v;
      }
    };
    auto writebuf = [&](int kc) {
      unsigned short* buf = arena + (kc & 1) * 8704;
      #pragma unroll
      for (int i = 0; i < 4; ++i) {
        short4_t p;
        p[0] = (short)f2bf(stg[i][0]); p[1] = (short)f2bf(stg[i][1]);
        p[2] = (short)f2bf(stg[i][2]); p[3] = (short)f2bf(stg[i][3]);
        *(short4_t*)&buf[(r0 + i * 16) * 136 + c4 * 4] = p;
      }
    };

    issue(0); writebuf(0);

    #pragma unroll
    for (int nb = 0; nb < 4; ++nb) acc_e[nb] = zero4;

    for (int kc = 0; kc < 7; ++kc) {
      __syncthreads();
      if (kc < 6) issue(kc + 1);
      const unsigned short* buf = arena + (kc & 1) * 8704;
      bool isStd = (kc == 6);
      #pragma unroll
      for (int ks = 0; ks < 4; ++ks) {
        const unsigned short* ap = isStd ? (wsf + (((w * 4 + ks) * 64 + l) << 3))
                                         : (wdf + (((w * 24 + kc * 4 + ks) * 64 + l) << 3));
        short8_t a = *(const short8_t*)ap;
        #pragma unroll
        for (int nb = 0; nb < 4; ++nb) {
          short8_t bb = *(const short8_t*)&buf[(nb * 16 + ln) * 136 + ks * 32 + g * 8];
          acc_e[nb] = __builtin_amdgcn_mfma_f32_16x16x32_bf16(a, bb, acc_e[nb], 0, 0, 0);
        }
      }
      if (kc < 6) writebuf(kc + 1);
    }
  }
  __syncthreads();  // last proj MFMAs (read act0) done -> reuse act0 as E

  // epilogue E: masked bias + embout f32 store + bf16 -> E (arena[0..17408))
  {
    unsigned short* E = arena;
    int k0 = w * 16 + g * 4;
    f32x4 bd4 = *(const f32x4*)(bdesc + k0);
    f32x4 bs4 = *(const f32x4*)(bstd + k0);
    #pragma unroll
    for (int nb = 0; nb < 4; ++nb) {
      int r = nb * 16 + ln;
      f32x4 e = acc_e[nb];
      if (r < nv) { f32x4 bias = (typeL[r] == 0) ? bd4 : bs4; e = e + bias; }
      else e = zero4;
      *(f32x4*)(embout + (size_t)(b * 512 + l0 + r) * 128 + k0) = e;
      short4_t p; p[0] = (short)f2bf(e[0]); p[1] = (short)f2bf(e[1]);
      p[2] = (short)f2bf(e[2]); p[3] = (short)f2bf(e[3]);
      *(short4_t*)&E[r * 136 + k0] = p;
    }
  }
  __syncthreads();  // E complete

  // ===== S1: H1T[c1][r] = cc[b][c1] + sum_k W1e[k][c1]*E[r][k]  (B from LDS E)
  #pragma unroll
  for (int mbi = 0; mbi < 4; ++mbi) {
    f32x4 ccv = *(const f32x4*)(cc + (size_t)b * 512 + (w * 4 + mbi) * 16 + g * 4);
    #pragma unroll
    for (int nb = 0; nb < 4; ++nb) acc[mbi][nb] = ccv;
  }
  {
    const unsigned short* E = arena;
    #pragma unroll
    for (int kk = 0; kk < 4; ++kk) {
      int ks = (kk + w) & 3;  // wave-staggered K order
      short8_t bfr[4];
      #pragma unroll
      for (int nb = 0; nb < 4; ++nb)
        bfr[nb] = *(const short8_t*)&E[(nb * 16 + ln) * 136 + ks * 32 + g * 8];
      #pragma unroll
      for (int mbi = 0; mbi < 4; ++mbi) {
        short8_t a = *(const short8_t*)(w1f + ((((w * 4 + mbi) * 4 + ks) * 64 + l) << 3));
        #pragma unroll
        for (int nb = 0; nb < 4; ++nb)
          acc[mbi][nb] = __builtin_amdgcn_mfma_f32_16x16x32_bf16(a, bfr[nb], acc[mbi][nb], 0, 0, 0);
      }
    }
  }
  __syncthreads();  // all E reads done -> arena free for h1

  // relu + pack H1 bf16 -> arena as swizzled [64][512]
  #pragma unroll
  for (int mbi = 0; mbi < 4; ++mbi) {
    int c0 = (w * 4 + mbi) * 16 + g * 4;
    #pragma unroll
    for (int nb = 0; nb < 4; ++nb) {
      int r = nb * 16 + ln;
      f32x4 v = acc[mbi][nb];
      short4_t p;
      p[0] = (short)f2bf(fmaxf(v[0], 0.f)); p[1] = (short)f2bf(fmaxf(v[1], 0.f));
      p[2] = (short)f2bf(fmaxf(v[2], 0.f)); p[3] = (short)f2bf(fmaxf(v[3], 0.f));
      *(short4_t*)&arena[r * 512 + (c0 ^ ((r & 7) << 3))] = p;
    }
  }
  __syncthreads();

  // ===== S2: H2T[c2][r] = b2[c2] + sum_c1 W2[c1][c2]*H1[r][c1]  (acc reused)
  #pragma unroll
  for (int mbi = 0; mbi < 4; ++mbi) {
    f32x4 b2v = *(const f32x4*)(b2 + (w * 4 + mbi) * 16 + g * 4);
    #pragma unroll
    for (int nb = 0; nb < 4; ++nb) acc[mbi][nb] = b2v;
  }
  #pragma unroll
  for (int kk = 0; kk < 16; ++kk) {
    int ks = (kk + 2 * w) & 15;  // wave-staggered K order
    short8_t bfr[4];
    #pragma unroll
    for (int nb = 0; nb < 4; ++nb) {
      int row = nb * 16 + ln;
      bfr[nb] = *(const short8_t*)&arena[row * 512 + ((ks * 32 + g * 8) ^ ((row & 7) << 3))];
    }
    #pragma unroll
    for (int mbi = 0; mbi < 4; ++mbi) {
      short8_t a = *(const short8_t*)(w2f + ((((w * 4 + mbi) * 16 + ks) * 64 + l) << 3));
      #pragma unroll
      for (int nb = 0; nb < 4; ++nb)
        acc[mbi][nb] = __builtin_amdgcn_mfma_f32_16x16x32_bf16(a, bfr[nb], acc[mbi][nb], 0, 0, 0);
    }
  }

  // ===== S3: q[r] = relu(b3 + sum_c2 relu(H2)*W3)
  float part[4] = {0.f, 0.f, 0.f, 0.f};
  #pragma unroll
  for (int mbi = 0; mbi < 4; ++mbi) {
    int c0 = (w * 4 + mbi) * 16 + g * 4;
    f32x4 w3v = *(const f32x4*)(W3 + c0);
    #pragma unroll
    for (int nb = 0; nb < 4; ++nb) {
      f32x4 v = acc[mbi][nb];
      part[nb] += fmaxf(v[0], 0.f) * w3v[0] + fmaxf(v[1], 0.f) * w3v[1]
                + fmaxf(v[2], 0.f) * w3v[2] + fmaxf(v[3], 0.f) * w3v[3];
    }
  }
  #pragma unroll
  for (int nb = 0; nb < 4; ++nb) {
    float p = part[nb];
    p += __shfl_xor(p, 16, 64);
    p += __shfl_xor(p, 32, 64);
    if (g == 0) qpart[w][nb * 16 + ln] = p;
  }
  __syncthreads();
  if (t < 64) {
    float q = qpart[0][t] + qpart[1][t] + qpart[2][t] + qpart[3][t]
            + qpart[4][t] + qpart[5][t] + qpart[6][t] + qpart[7][t] + b3[0];
    qout[(size_t)b * 512 + l0 + t] = fmaxf(q, 0.f);
  }
}

extern "C" void kernel_launch(void* const* d_in, const int* in_sizes, int n_in,
                              void* d_out, int out_size, void* d_ws, size_t ws_size,
                              hipStream_t stream) {
  (void)in_sizes; (void)n_in; (void)out_size; (void)ws_size;
  const float* instr  = (const float*)d_in[0];
  const float* state  = (const float*)d_in[1];
  const float* hidden = (const float*)d_in[2];
  const float* adesc  = (const float*)d_in[3];
  const float* astd   = (const float*)d_in[4];
  const int*   tids   = (const int*)d_in[5];
  const int*   lens   = (const int*)d_in[6];
  const float* Wd = (const float*)d_in[7];
  const float* bd = (const float*)d_in[8];
  const float* Ws = (const float*)d_in[9];
  const float* bs = (const float*)d_in[10];
  const float* W1 = (const float*)d_in[11];
  const float* b1 = (const float*)d_in[12];
  const float* W2 = (const float*)d_in[13];
  const float* b2 = (const float*)d_in[14];
  const float* W3 = (const float*)d_in[15];
  const float* b3 = (const float*)d_in[16];

  float* qout = (float*)d_out;
  float* embout = qout + 128 * 512;

  char* ws = (char*)d_ws;
  unsigned short* wdf  = (unsigned short*)(ws);             // 196608 B
  unsigned short* wsf  = (unsigned short*)(ws + 196608);    //  32768 B
  unsigned short* w1f  = (unsigned short*)(ws + 229376);    // 131072 B
  unsigned short* w2f  = (unsigned short*)(ws + 360448);    // 524288 B
  unsigned short* w1cf = (unsigned short*)(ws + 884736);    // 1179648 B
  float* cc   = (float*)(ws + 2064384);                     // 262144 B
  float* qinv = (float*)(ws + 2326528);                     // 512 B

  prep_pack<<<256, 256, 0, stream>>>(Wd, Ws, W1, W2, wdf, wsf, w1f, w2f, w1cf);
  cc_gemm<<<dim3(8, 4), 256, 0, stream>>>(instr, state, hidden, w1cf, b1, cc);
  hipMemsetAsync(qinv, 0, 128 * sizeof(float), stream);
  qinv_gemm<<<dim3(8, 4), 256, 0, stream>>>(cc, w2f, b2, W3, qinv);
  dim3 grid(8, 128);
  fused_main<<<grid, 512, 0, stream>>>(adesc, astd, tids, lens, bd, bs, b2, W3, b3,
                                       wdf, wsf, w1f, w2f, cc, qinv, embout, qout);
}